// Round 14
// baseline (478.760 us; speedup 1.0000x reference)
//
#include <hip/hip_runtime.h>
#include <stdint.h>

// LSTMConv via MFMA — SINGLE-BARRIER step + full-frag prefetch + deep acc
// rotation. R13 ruled out vmcnt drain; R12: busy-sum <=80%, stall >=20%.
// This round: (1) one lgkm-barrier per step (was 2) -> window doubles,
// waves can slip; (2) all 12 B-frags ds_read before any MFMA per chain ->
// LDS latency paid once; (3) MFMA loops kt->nt->gi -> acc revisit distance
// 8 MFMAs (~39cy) clears RAW-latency stalls. Accumulation order per acc
// unchanged -> bit-identical numerics.
//
// Step t (buf parity: read buf[cur]={x_t,h(t-1)}, write buf[nxt]):
//   gather-issue x(t+1); GEMM_A(t)+FC_A(t-1); GEMM_B(t)+FC_B(t-1);
//   cell_A(t)->hB[nxt]; cell_B(t)->hB[nxt]; FC stores; x-pack; barrier.
// Weights + bias persistent in VGPRs; x/h LDS pre-packed as MFMA B-frags
// (conflict-free ds_read_b128), double-buffered. exp2-folded activations,
// raw v_exp_f32.

#define T_STEPS 32
#define C_IN    64
#define HID     128
#define OUT_F   64
#define BP      64
#define NBLK    256            // 16384 / BP
#define NTHR    512            // 8 waves

typedef __attribute__((ext_vector_type(8))) short short8_t;
typedef __attribute__((ext_vector_type(4))) short short4_t;
typedef __attribute__((ext_vector_type(4))) float float4_t;
typedef __attribute__((ext_vector_type(4))) unsigned int uint4_t;

#define L2E 1.44269504088896340736f

__device__ __forceinline__ short f2bf(float f) {
    uint32_t u = __builtin_bit_cast(uint32_t, f);
    u += 0x7fff + ((u >> 16) & 1);   // RNE
    return (short)(u >> 16);
}
__device__ __forceinline__ uint32_t cvt_pk(float lo, float hi) {
    uint32_t r;
    asm("v_cvt_pk_bf16_f32 %0, %1, %2" : "=v"(r) : "v"(lo), "v"(hi));
    return r;
}
// raw-trans activations: one v_exp_f32 + one v_rcp_f32 each
__device__ __forceinline__ float sig2(float a) {   // a pre-scaled by L2E
    return __builtin_amdgcn_rcpf(1.0f + __builtin_amdgcn_exp2f(-a));
}
__device__ __forceinline__ float th2(float a) {    // a pre-scaled by 2*L2E
    return fmaf(-2.0f,
                __builtin_amdgcn_rcpf(1.0f + __builtin_amdgcn_exp2f(a)),
                1.0f);
}
// barrier that waits ONLY on LDS ops (lgkmcnt), leaving VMEM in flight
__device__ __forceinline__ void barrier_lgkm() {
    asm volatile("s_waitcnt lgkmcnt(0)" ::: "memory");
    __builtin_amdgcn_s_barrier();
    asm volatile("" ::: "memory");
}

__global__ __launch_bounds__(NTHR, 2) void lstmconv_mfma(
    const float* __restrict__ feats,
    const float* __restrict__ W_ih,
    const float* __restrict__ W_hh,
    const float* __restrict__ b_ih,
    const float* __restrict__ b_hh,
    const float* __restrict__ fc_w,
    const float* __restrict__ fc_b,
    float* __restrict__ out)
{
    __shared__ __align__(16) short xB[2][8][512];    // 16 KB
    __shared__ __align__(16) short hB[2][16][512];   // 32 KB

    const int tid  = threadIdx.x;
    const int lane = tid & 63;
    const int wv   = tid >> 6;       // wave 0..7; owns gate rows 16wv..16wv+16
    const int i16  = lane & 15;
    const int g4   = lane >> 4;
    const int p0   = blockIdx.x * BP;

    // ---------- one-time init ----------
    for (int i = tid; i < 2 * 16 * 512 / 2; i += NTHR)
        ((uint32_t*)hB)[i] = 0u;                     // h_{-1}=0

    // Gate-W A-fragments, persistent, log2e-scaled:
    // row = 128*gi + 16*wv + i16 ; k = 32*kt + 8*g4 + e  (kt<2 -> W_ih)
    short8_t wfrag[4][6];
    float4_t bias_r[4];
    #pragma unroll
    for (int gi = 0; gi < 4; ++gi) {
        int row = 128 * gi + 16 * wv + i16;
        float sc = (gi == 2) ? 2.0f * L2E : L2E;
        #pragma unroll
        for (int kt = 0; kt < 6; ++kt) {
            int kk = 32 * kt + 8 * g4;
            const float* src = (kt < 2) ? &W_ih[row * C_IN + kk]
                                        : &W_hh[row * HID + (kk - 64)];
            short8_t f;
            #pragma unroll
            for (int e = 0; e < 8; ++e) f[e] = f2bf(src[e] * sc);
            wfrag[gi][kt] = f;
        }
        int g0 = 128 * gi + 16 * wv + 4 * g4;
        float4_t bi = *(const float4_t*)&b_ih[g0];
        float4_t bh = *(const float4_t*)&b_hh[g0];
        #pragma unroll
        for (int r = 0; r < 4; ++r) bias_r[gi][r] = (bi[r] + bh[r]) * sc;
    }

    // FC: wave -> m-tile m2=wv&3 (out rows 16m2..+16), local n-tile nl=wv>>2.
    const int m2  = wv & 3;
    const int nl  = wv >> 2;         // 0 or 1 within the chain
    short8_t fcfrag[4];
    #pragma unroll
    for (int kt = 0; kt < 4; ++kt) {
        int kk = 32 * kt + 8 * g4;
        const float* src = &fc_w[(16 * m2 + i16) * HID + kk];
        short8_t f;
        #pragma unroll
        for (int e = 0; e < 8; ++e) f[e] = f2bf(src[e]);
        fcfrag[kt] = f;
    }
    const float4_t fcb = *(const float4_t*)&fc_b[16 * m2 + 4 * g4];

    // gather: thread loads channels c = 8*wv + e, pixel p = lane
    const int prow  = 2 * (p0 >> 7) + 1;
    const int pcol0 = 2 * (p0 & 127) + 1;
    const int gbase = prow * 256 + pcol0 + 2 * lane;
    const int xtile = (wv >> 2) * 4 + (lane >> 4);           // kt*4 + nt
    const int xoff  = ((lane & 15) + 16 * (wv & 3)) * 8;
    const int htile_base = (wv >> 1) * 4;                    // + global nt
    const int hoff  = (i16 + 16 * (2 * (wv & 1) + (g4 >> 1))) * 8 + 4 * (g4 & 1);

    // prologue: gather x_0 -> xB[0]
    {
        float g[8];
        #pragma unroll
        for (int e = 0; e < 8; ++e)
            g[e] = feats[((size_t)(8 * wv + e) << 16) + gbase];
        uint4_t pk = { cvt_pk(g[0], g[1]), cvt_pk(g[2], g[3]),
                       cvt_pk(g[4], g[5]), cvt_pk(g[6], g[7]) };
        *(uint4_t*)&xB[0][xtile][xoff] = pk;
    }

    float4_t accA[4][2], accB[4][2], cA[2], cB[2];
    #pragma unroll
    for (int nt = 0; nt < 2; ++nt) {
        cA[nt] = (float4_t){0.f, 0.f, 0.f, 0.f};
        cB[nt] = (float4_t){0.f, 0.f, 0.f, 0.f};
    }

    // store FC result for step tf of `chain`
    auto store_fc = [&](int tf, int chain, const float4_t& facc) {
        int ntg = chain * 2 + nl;
        #pragma unroll
        for (int r = 0; r < 4; ++r)
            out[((size_t)(tf * OUT_F + 16 * m2 + 4 * g4 + r) << 14)
                + p0 + 16 * ntg + i16] = facc[r];
    };

    // standalone FC (epilogue): h in hB[hb]
    auto do_fc = [&](int tf, int hb, int chain) {
        int ntg = chain * 2 + nl;
        float4_t facc = fcb;
        #pragma unroll
        for (int kt = 0; kt < 4; ++kt) {
            short8_t b = *(const short8_t*)&hB[hb][kt * 4 + ntg][lane * 8];
            facc = __builtin_amdgcn_mfma_f32_16x16x32_bf16(
                fcfrag[kt], b, facc, 0, 0, 0);
        }
        store_fc(tf, chain, facc);
    };

    // gates = bias + W @ [x(xb); h(hb)] for `chain`; FC(t-1) merged on the
    // shared h fragments (kt 2..5, nt==nl). ALL 12 frags loaded first;
    // MFMA order kt->nt->gi (acc revisit distance 8).
    auto gemm = [&](float4_t (&acc)[4][2], int xb, int hb, int chain,
                    float4_t& facc, bool fc_on) {
        short8_t bf[2][6];
        #pragma unroll
        for (int nt = 0; nt < 2; ++nt) {
            int ntg = chain * 2 + nt;
            #pragma unroll
            for (int kt = 0; kt < 6; ++kt) {
                const short* src = (kt < 2) ? &xB[xb][kt * 4 + ntg][0]
                                            : &hB[hb][(kt - 2) * 4 + ntg][0];
                bf[nt][kt] = *(const short8_t*)&src[lane * 8];
            }
        }
        #pragma unroll
        for (int gi = 0; gi < 4; ++gi)
            #pragma unroll
            for (int nt = 0; nt < 2; ++nt) acc[gi][nt] = bias_r[gi];
        #pragma unroll
        for (int kt = 0; kt < 6; ++kt)
            #pragma unroll
            for (int nt = 0; nt < 2; ++nt)
                #pragma unroll
                for (int gi = 0; gi < 4; ++gi)
                    acc[gi][nt] = __builtin_amdgcn_mfma_f32_16x16x32_bf16(
                        wfrag[gi][kt], bf[nt][kt], acc[gi][nt], 0, 0, 0);
        if (fc_on) {
            #pragma unroll
            for (int kt = 2; kt < 6; ++kt)
                facc = __builtin_amdgcn_mfma_f32_16x16x32_bf16(
                    fcfrag[kt - 2], bf[nl][kt], facc, 0, 0, 0);
        }
    };

    // cell update (i,f,g,o) for `chain`; writes h into hB[hb]
    auto cell = [&](float4_t (&acc)[4][2], float4_t (&c)[2], int hb, int chain) {
        #pragma unroll
        for (int nt = 0; nt < 2; ++nt) {
            float4_t cv = c[nt];
            float hv[4];
            #pragma unroll
            for (int r = 0; r < 4; ++r) {
                float ig = sig2(acc[0][nt][r]);
                float fg = sig2(acc[1][nt][r]);
                float cand = th2(acc[2][nt][r]);
                float og = sig2(acc[3][nt][r]);
                float cn = fmaf(fg, cv[r], ig * cand);
                cv[r] = cn;
                hv[r] = og * th2(cn * (2.0f * L2E));
            }
            c[nt] = cv;
            uint32_t h0 = cvt_pk(hv[0], hv[1]);
            uint32_t h1 = cvt_pk(hv[2], hv[3]);
            uint32_t* dst = (uint32_t*)&hB[hb][htile_base + chain * 2 + nt][hoff];
            dst[0] = h0; dst[1] = h1;
        }
    };

    __syncthreads();   // cold: xB[0] ready, hB zeroed

    #pragma unroll 1
    for (int t = 0; t < T_STEPS; ++t) {
        const int cur = t & 1;
        const int nxt = cur ^ 1;

        // ---- issue gather loads for x(t+1)
        float g[8];
        if (t < T_STEPS - 1) {
            #pragma unroll
            for (int e = 0; e < 8; ++e)
                g[e] = feats[((size_t)((t + 1) * C_IN + 8 * wv + e) << 16) + gbase];
        }

        // ---- GEMMs (read buf[cur]: x_t, h(t-1)); FC(t-1) merged
        float4_t faccA = fcb, faccB = fcb;
        gemm(accA, cur, cur, 0, faccA, t > 0);
        gemm(accB, cur, cur, 1, faccB, t > 0);

        // ---- cells (write h_t -> hB[nxt]); adjacent to GEMM_B for overlap
        cell(accA, cA, nxt, 0);
        cell(accB, cB, nxt, 1);

        if (t > 0) {
            store_fc(t - 1, 0, faccA);
            store_fc(t - 1, 1, faccB);
        }

        // ---- pack & store x(t+1) -> xB[nxt]
        if (t < T_STEPS - 1) {
            uint4_t pk = { cvt_pk(g[0], g[1]), cvt_pk(g[2], g[3]),
                           cvt_pk(g[4], g[5]), cvt_pk(g[6], g[7]) };
            *(uint4_t*)&xB[nxt][xtile][xoff] = pk;
        }

        barrier_lgkm();   // ONE barrier per step
    }

    // epilogue: FC of both chains for t=31 (h(31) in hB[0], t=31 nxt=0)
    do_fc(T_STEPS - 1, 0, 0);
    do_fc(T_STEPS - 1, 0, 1);
}

extern "C" void kernel_launch(void* const* d_in, const int* in_sizes, int n_in,
                              void* d_out, int out_size, void* d_ws, size_t ws_size,
                              hipStream_t stream) {
    const float* feats = (const float*)d_in[0];
    const float* W_ih  = (const float*)d_in[1];
    const float* W_hh  = (const float*)d_in[2];
    const float* b_ih  = (const float*)d_in[3];
    const float* b_hh  = (const float*)d_in[4];
    const float* fc_w  = (const float*)d_in[5];
    const float* fc_b  = (const float*)d_in[6];
    float* out = (float*)d_out;

    lstmconv_mfma<<<NBLK, NTHR, 0, stream>>>(feats, W_ih, W_hh, b_ih, b_hh,
                                             fc_w, fc_b, out);
}

// Round 15
// 170.304 us; speedup vs baseline: 2.8112x; 2.8112x over previous
//
#include <hip/hip_runtime.h>
#include <stdint.h>

// LSTMConv via MFMA — R13 base (best, 156.8us) + two work cuts:
// (1) TRANS FUSION: i*g = (E2-1)*rcp((1+e0)(1+E2)), h = (Ec-1)*rcp((1+e3)(1+Ec))
//     -> 5 exp + 3 rcp per element (was 5+5). Safe for |gate|<88.
// (2) GATHER ADDR HOIST: per-lane int32 offsets precomputed; per-step
//     advance is one uniform pointer bump (SGPR add), loads are single
//     global_load_dword each.
// R14 (single-barrier + full prefetch) reverted: scratch spill, 3x slower.
//
// Chain A = p 0..31 (n-tiles 0,1), chain B = p 32..63 (n-tiles 2,3).
//   P1: gather-issue(t+1), GEMM_A(t)+FC_A(t-1) merged, cell_B(t-1)
//   P2: GEMM_B(t)+FC_B(t-1) merged, cell_A(t), x-pack(t+1)
// Weights + bias persistent in VGPRs; x/h LDS pre-packed as MFMA B-frags
// (conflict-free ds_read_b128), double-buffered; lgkm-only barriers.

#define T_STEPS 32
#define C_IN    64
#define HID     128
#define OUT_F   64
#define BP      64
#define NBLK    256            // 16384 / BP
#define NTHR    512            // 8 waves

typedef __attribute__((ext_vector_type(8))) short short8_t;
typedef __attribute__((ext_vector_type(4))) short short4_t;
typedef __attribute__((ext_vector_type(4))) float float4_t;
typedef __attribute__((ext_vector_type(4))) unsigned int uint4_t;

#define L2E 1.44269504088896340736f

__device__ __forceinline__ short f2bf(float f) {
    uint32_t u = __builtin_bit_cast(uint32_t, f);
    u += 0x7fff + ((u >> 16) & 1);   // RNE
    return (short)(u >> 16);
}
__device__ __forceinline__ uint32_t cvt_pk(float lo, float hi) {
    uint32_t r;
    asm("v_cvt_pk_bf16_f32 %0, %1, %2" : "=v"(r) : "v"(lo), "v"(hi));
    return r;
}
// barrier that waits ONLY on LDS ops (lgkmcnt), leaving VMEM in flight
__device__ __forceinline__ void barrier_lgkm() {
    asm volatile("s_waitcnt lgkmcnt(0)" ::: "memory");
    __builtin_amdgcn_s_barrier();
    asm volatile("" ::: "memory");
}

__global__ __launch_bounds__(NTHR, 2) void lstmconv_mfma(
    const float* __restrict__ feats,
    const float* __restrict__ W_ih,
    const float* __restrict__ W_hh,
    const float* __restrict__ b_ih,
    const float* __restrict__ b_hh,
    const float* __restrict__ fc_w,
    const float* __restrict__ fc_b,
    float* __restrict__ out)
{
    __shared__ __align__(16) short xB[2][8][512];    // 16 KB
    __shared__ __align__(16) short hB[2][16][512];   // 32 KB

    const int tid  = threadIdx.x;
    const int lane = tid & 63;
    const int wv   = tid >> 6;       // wave 0..7; owns gate rows 16wv..16wv+16
    const int i16  = lane & 15;
    const int g4   = lane >> 4;
    const int p0   = blockIdx.x * BP;

    // ---------- one-time init ----------
    for (int i = tid; i < 2 * 16 * 512 / 2; i += NTHR)
        ((uint32_t*)hB)[i] = 0u;                     // h_{-1}=0 in BOTH bufs

    // Gate-W A-fragments, persistent, log2e-scaled:
    // row = 128*gi + 16*wv + i16 ; k = 32*kt + 8*g4 + e  (kt<2 -> W_ih)
    short8_t wfrag[4][6];
    float4_t bias_r[4];
    #pragma unroll
    for (int gi = 0; gi < 4; ++gi) {
        int row = 128 * gi + 16 * wv + i16;
        float sc = (gi == 2) ? 2.0f * L2E : L2E;
        #pragma unroll
        for (int kt = 0; kt < 6; ++kt) {
            int kk = 32 * kt + 8 * g4;
            const float* src = (kt < 2) ? &W_ih[row * C_IN + kk]
                                        : &W_hh[row * HID + (kk - 64)];
            short8_t f;
            #pragma unroll
            for (int e = 0; e < 8; ++e) f[e] = f2bf(src[e] * sc);
            wfrag[gi][kt] = f;
        }
        int g0 = 128 * gi + 16 * wv + 4 * g4;
        float4_t bi = *(const float4_t*)&b_ih[g0];
        float4_t bh = *(const float4_t*)&b_hh[g0];
        #pragma unroll
        for (int r = 0; r < 4; ++r) bias_r[gi][r] = (bi[r] + bh[r]) * sc;
    }

    // FC: wave -> m-tile m2=wv&3 (out rows 16m2..+16), local n-tile nl=wv>>2.
    const int m2  = wv & 3;
    const int nl  = wv >> 2;         // 0 or 1 within the chain
    short8_t fcfrag[4];
    #pragma unroll
    for (int kt = 0; kt < 4; ++kt) {
        int kk = 32 * kt + 8 * g4;
        const float* src = &fc_w[(16 * m2 + i16) * HID + kk];
        short8_t f;
        #pragma unroll
        for (int e = 0; e < 8; ++e) f[e] = f2bf(src[e]);
        fcfrag[kt] = f;
    }
    const float4_t fcb = *(const float4_t*)&fc_b[16 * m2 + 4 * g4];

    // gather: thread loads channels c = 8*wv + e, pixel p = lane.
    // Per-lane int32 offsets precomputed; per-step advance = uniform ptr bump.
    const int prow  = 2 * (p0 >> 7) + 1;
    const int pcol0 = 2 * (p0 & 127) + 1;
    const int gbase = prow * 256 + pcol0 + 2 * lane;
    int goff[8];
    #pragma unroll
    for (int e = 0; e < 8; ++e)
        goff[e] = ((8 * wv + e) << 16) + gbase;
    const int xtile = (wv >> 2) * 4 + (lane >> 4);           // kt*4 + nt
    const int xoff  = ((lane & 15) + 16 * (wv & 3)) * 8;
    const int htile_base = (wv >> 1) * 4;                    // + global nt
    const int hoff  = (i16 + 16 * (2 * (wv & 1) + (g4 >> 1))) * 8 + 4 * (g4 & 1);

    // prologue: gather x_0 -> xB[0]
    {
        float g[8];
        #pragma unroll
        for (int e = 0; e < 8; ++e) g[e] = feats[goff[e]];
        uint4_t pk = { cvt_pk(g[0], g[1]), cvt_pk(g[2], g[3]),
                       cvt_pk(g[4], g[5]), cvt_pk(g[6], g[7]) };
        *(uint4_t*)&xB[0][xtile][xoff] = pk;
    }

    float4_t accA[4][2], accB[4][2], cA[2], cB[2];
    #pragma unroll
    for (int nt = 0; nt < 2; ++nt) {
        cA[nt] = (float4_t){0.f, 0.f, 0.f, 0.f};
        cB[nt] = (float4_t){0.f, 0.f, 0.f, 0.f};
    }

    // store FC result for step tf of `chain`
    auto store_fc = [&](int tf, int chain, const float4_t& facc) {
        int ntg = chain * 2 + nl;
        #pragma unroll
        for (int r = 0; r < 4; ++r)
            out[((size_t)(tf * OUT_F + 16 * m2 + 4 * g4 + r) << 14)
                + p0 + 16 * ntg + i16] = facc[r];
    };

    // standalone FC (epilogue): h in hB[hb]
    auto do_fc = [&](int tf, int hb, int chain) {
        int ntg = chain * 2 + nl;
        float4_t facc = fcb;
        #pragma unroll
        for (int kt = 0; kt < 4; ++kt) {
            short8_t b = *(const short8_t*)&hB[hb][kt * 4 + ntg][lane * 8];
            facc = __builtin_amdgcn_mfma_f32_16x16x32_bf16(
                fcfrag[kt], b, facc, 0, 0, 0);
        }
        store_fc(tf, chain, facc);
    };

    // gates = bias + W @ [x(xb); h(hb)] for `chain`; FC(t-1) merged on the
    // shared h fragments (kt 2..5) when nt == nl.
    auto gemm = [&](float4_t (&acc)[4][2], int xb, int hb, int chain,
                    float4_t& facc, bool fc_on) {
        #pragma unroll
        for (int gi = 0; gi < 4; ++gi)
            #pragma unroll
            for (int nt = 0; nt < 2; ++nt) acc[gi][nt] = bias_r[gi];
        #pragma unroll
        for (int nt = 0; nt < 2; ++nt) {
            int ntg = chain * 2 + nt;
            short8_t bf[6];
            #pragma unroll
            for (int kt = 0; kt < 6; ++kt) {
                const short* src = (kt < 2) ? &xB[xb][kt * 4 + ntg][0]
                                            : &hB[hb][(kt - 2) * 4 + ntg][0];
                bf[kt] = *(const short8_t*)&src[lane * 8];
            }
            #pragma unroll
            for (int kt = 0; kt < 6; ++kt)
                #pragma unroll
                for (int gi = 0; gi < 4; ++gi)
                    acc[gi][nt] = __builtin_amdgcn_mfma_f32_16x16x32_bf16(
                        wfrag[gi][kt], bf[kt], acc[gi][nt], 0, 0, 0);
            if (fc_on && nt == nl) {
                #pragma unroll
                for (int kt = 2; kt < 6; ++kt)
                    facc = __builtin_amdgcn_mfma_f32_16x16x32_bf16(
                        fcfrag[kt - 2], bf[kt], facc, 0, 0, 0);
            }
        }
    };

    // cell update (i,f,g,o), trans-fused: 5 exp + 3 rcp per element.
    // i*g = (E2-1)*rcp((1+e0)(1+E2));  h = o*tanh(cn) = (Ec-1)*rcp((1+e3)(1+Ec))
    auto cell = [&](float4_t (&acc)[4][2], float4_t (&c)[2], int hb, int chain) {
        #pragma unroll
        for (int nt = 0; nt < 2; ++nt) {
            float4_t cv = c[nt];
            float hv[4];
            #pragma unroll
            for (int r = 0; r < 4; ++r) {
                float e0 = __builtin_amdgcn_exp2f(-acc[0][nt][r]);  // i-gate
                float e1 = __builtin_amdgcn_exp2f(-acc[1][nt][r]);  // f-gate
                float E2 = __builtin_amdgcn_exp2f( acc[2][nt][r]);  // cand (2L2E)
                float e3 = __builtin_amdgcn_exp2f(-acc[3][nt][r]);  // o-gate
                float ig_cand = (E2 - 1.0f) *
                    __builtin_amdgcn_rcpf((1.0f + e0) * (1.0f + E2));
                float cn = fmaf(cv[r], __builtin_amdgcn_rcpf(1.0f + e1),
                                ig_cand);
                cv[r] = cn;
                float Ec = __builtin_amdgcn_exp2f(cn * (2.0f * L2E));
                hv[r] = (Ec - 1.0f) *
                    __builtin_amdgcn_rcpf((1.0f + e3) * (1.0f + Ec));
            }
            c[nt] = cv;
            uint32_t h0 = cvt_pk(hv[0], hv[1]);
            uint32_t h1 = cvt_pk(hv[2], hv[3]);
            uint32_t* dst = (uint32_t*)&hB[hb][htile_base + chain * 2 + nt][hoff];
            dst[0] = h0; dst[1] = h1;
        }
    };

    __syncthreads();   // cold: xB[0] ready, hB zeroed

    const float* fbase = feats;
    #pragma unroll 1
    for (int t = 0; t < T_STEPS; ++t) {
        const int cur = t & 1;
        const int nxt = cur ^ 1;   // holds h(t-1) of both chains
        fbase += (size_t)C_IN << 16;   // advance to timestep t+1 (uniform)

        // ======== P1: GEMM_A(t)+FC_A(t-1) + cell_B(t-1) ========
        float g[8];
        if (t < T_STEPS - 1) {
            #pragma unroll
            for (int e = 0; e < 8; ++e) g[e] = fbase[goff[e]];
        }
        float4_t faccA = fcb;
        gemm(accA, cur, nxt, 0, faccA, t > 0);
        if (t > 0) store_fc(t - 1, 0, faccA);
        if (t > 0) cell(accB, cB, nxt, 1);   // writes hB[nxt] tiles {2,3}

        barrier_lgkm();   // B1

        // ======== P2: GEMM_B(t)+FC_B(t-1) + cell_A(t) ========
        float4_t faccB = fcb;
        gemm(accB, cur, nxt, 1, faccB, t > 0);
        if (t > 0) store_fc(t - 1, 1, faccB);
        cell(accA, cA, cur, 0);              // writes hB[cur] tiles {0,1}

        if (t < T_STEPS - 1) {
            uint4_t pk = { cvt_pk(g[0], g[1]), cvt_pk(g[2], g[3]),
                           cvt_pk(g[4], g[5]), cvt_pk(g[6], g[7]) };
            *(uint4_t*)&xB[nxt][xtile][xoff] = pk;
        }

        barrier_lgkm();   // B2
    }

    // epilogue: cell_B(31) -> hB[1]; FC of both chains for t=31 (h in hB[1])
    cell(accB, cB, 1, 1);
    __syncthreads();   // cold
    do_fc(T_STEPS - 1, 1, 0);
    do_fc(T_STEPS - 1, 1, 1);
}

extern "C" void kernel_launch(void* const* d_in, const int* in_sizes, int n_in,
                              void* d_out, int out_size, void* d_ws, size_t ws_size,
                              hipStream_t stream) {
    const float* feats = (const float*)d_in[0];
    const float* W_ih  = (const float*)d_in[1];
    const float* W_hh  = (const float*)d_in[2];
    const float* b_ih  = (const float*)d_in[3];
    const float* b_hh  = (const float*)d_in[4];
    const float* fc_w  = (const float*)d_in[5];
    const float* fc_b  = (const float*)d_in[6];
    float* out = (float*)d_out;

    lstmconv_mfma<<<NBLK, NTHR, 0, stream>>>(feats, W_ih, W_hh, b_ih, b_hh,
                                             fc_w, fc_b, out);
}

// Round 16
// 157.535 us; speedup vs baseline: 3.0391x; 1.0811x over previous
//
#include <hip/hip_runtime.h>
#include <stdint.h>

// LSTMConv via MFMA — R13 (BEST: 156.8us), restored verbatim after R15's
// work-cut experiments regressed (trans fusion deepened serial chains;
// latency-bound at 2 waves/SIMD -> chain depth > issue count).
// Structure: two phase-shifted chains, FC merged into gate-GEMM h-frags,
// lgkm-only barriers (2/step), raw v_exp_f32 activations, weights+bias
// persistent in VGPRs, x/h LDS pre-packed as MFMA B-frags, double-buffered.
//
// Chain A = p 0..31 (n-tiles 0,1), chain B = p 32..63 (n-tiles 2,3).
//   P1: gather-issue(t+1), GEMM_A(t)+FC_A(t-1) merged, cell_B(t-1)
//   P2: GEMM_B(t)+FC_B(t-1) merged, cell_A(t), x-pack(t+1)

#define T_STEPS 32
#define C_IN    64
#define HID     128
#define OUT_F   64
#define BP      64
#define NBLK    256            // 16384 / BP
#define NTHR    512            // 8 waves

typedef __attribute__((ext_vector_type(8))) short short8_t;
typedef __attribute__((ext_vector_type(4))) short short4_t;
typedef __attribute__((ext_vector_type(4))) float float4_t;
typedef __attribute__((ext_vector_type(4))) unsigned int uint4_t;

#define L2E 1.44269504088896340736f

__device__ __forceinline__ short f2bf(float f) {
    uint32_t u = __builtin_bit_cast(uint32_t, f);
    u += 0x7fff + ((u >> 16) & 1);   // RNE
    return (short)(u >> 16);
}
__device__ __forceinline__ uint32_t cvt_pk(float lo, float hi) {
    uint32_t r;
    asm("v_cvt_pk_bf16_f32 %0, %1, %2" : "=v"(r) : "v"(lo), "v"(hi));
    return r;
}
// raw-trans activations: one v_exp_f32 + one v_rcp_f32 each
__device__ __forceinline__ float sig2(float a) {   // a pre-scaled by L2E
    return __builtin_amdgcn_rcpf(1.0f + __builtin_amdgcn_exp2f(-a));
}
__device__ __forceinline__ float th2(float a) {    // a pre-scaled by 2*L2E
    return fmaf(-2.0f,
                __builtin_amdgcn_rcpf(1.0f + __builtin_amdgcn_exp2f(a)),
                1.0f);
}
// barrier that waits ONLY on LDS ops (lgkmcnt), leaving VMEM in flight
__device__ __forceinline__ void barrier_lgkm() {
    asm volatile("s_waitcnt lgkmcnt(0)" ::: "memory");
    __builtin_amdgcn_s_barrier();
    asm volatile("" ::: "memory");
}

__global__ __launch_bounds__(NTHR, 2) void lstmconv_mfma(
    const float* __restrict__ feats,
    const float* __restrict__ W_ih,
    const float* __restrict__ W_hh,
    const float* __restrict__ b_ih,
    const float* __restrict__ b_hh,
    const float* __restrict__ fc_w,
    const float* __restrict__ fc_b,
    float* __restrict__ out)
{
    __shared__ __align__(16) short xB[2][8][512];    // 16 KB
    __shared__ __align__(16) short hB[2][16][512];   // 32 KB

    const int tid  = threadIdx.x;
    const int lane = tid & 63;
    const int wv   = tid >> 6;       // wave 0..7; owns gate rows 16wv..16wv+16
    const int i16  = lane & 15;
    const int g4   = lane >> 4;
    const int p0   = blockIdx.x * BP;

    // ---------- one-time init ----------
    for (int i = tid; i < 2 * 16 * 512 / 2; i += NTHR)
        ((uint32_t*)hB)[i] = 0u;                     // h_{-1}=0 in BOTH bufs

    // Gate-W A-fragments, persistent, log2e-scaled:
    // row = 128*gi + 16*wv + i16 ; k = 32*kt + 8*g4 + e  (kt<2 -> W_ih)
    short8_t wfrag[4][6];
    float4_t bias_r[4];
    #pragma unroll
    for (int gi = 0; gi < 4; ++gi) {
        int row = 128 * gi + 16 * wv + i16;
        float sc = (gi == 2) ? 2.0f * L2E : L2E;
        #pragma unroll
        for (int kt = 0; kt < 6; ++kt) {
            int kk = 32 * kt + 8 * g4;
            const float* src = (kt < 2) ? &W_ih[row * C_IN + kk]
                                        : &W_hh[row * HID + (kk - 64)];
            short8_t f;
            #pragma unroll
            for (int e = 0; e < 8; ++e) f[e] = f2bf(src[e] * sc);
            wfrag[gi][kt] = f;
        }
        int g0 = 128 * gi + 16 * wv + 4 * g4;
        float4_t bi = *(const float4_t*)&b_ih[g0];
        float4_t bh = *(const float4_t*)&b_hh[g0];
        #pragma unroll
        for (int r = 0; r < 4; ++r) bias_r[gi][r] = (bi[r] + bh[r]) * sc;
    }

    // FC: wave -> m-tile m2=wv&3 (out rows 16m2..+16), local n-tile nl=wv>>2.
    const int m2  = wv & 3;
    const int nl  = wv >> 2;         // 0 or 1 within the chain
    short8_t fcfrag[4];
    #pragma unroll
    for (int kt = 0; kt < 4; ++kt) {
        int kk = 32 * kt + 8 * g4;
        const float* src = &fc_w[(16 * m2 + i16) * HID + kk];
        short8_t f;
        #pragma unroll
        for (int e = 0; e < 8; ++e) f[e] = f2bf(src[e]);
        fcfrag[kt] = f;
    }
    const float4_t fcb = *(const float4_t*)&fc_b[16 * m2 + 4 * g4];

    // gather: thread loads channels c = 8*wv + e, pixel p = lane
    const int prow  = 2 * (p0 >> 7) + 1;
    const int pcol0 = 2 * (p0 & 127) + 1;
    const int gbase = prow * 256 + pcol0 + 2 * lane;
    const int xtile = (wv >> 2) * 4 + (lane >> 4);           // kt*4 + nt
    const int xoff  = ((lane & 15) + 16 * (wv & 3)) * 8;
    const int htile_base = (wv >> 1) * 4;                    // + global nt
    const int hoff  = (i16 + 16 * (2 * (wv & 1) + (g4 >> 1))) * 8 + 4 * (g4 & 1);

    // prologue: gather x_0 -> xB[0]
    {
        float g[8];
        #pragma unroll
        for (int e = 0; e < 8; ++e)
            g[e] = feats[((size_t)(8 * wv + e) << 16) + gbase];
        uint4_t pk = { cvt_pk(g[0], g[1]), cvt_pk(g[2], g[3]),
                       cvt_pk(g[4], g[5]), cvt_pk(g[6], g[7]) };
        *(uint4_t*)&xB[0][xtile][xoff] = pk;
    }

    float4_t accA[4][2], accB[4][2], cA[2], cB[2];
    #pragma unroll
    for (int nt = 0; nt < 2; ++nt) {
        cA[nt] = (float4_t){0.f, 0.f, 0.f, 0.f};
        cB[nt] = (float4_t){0.f, 0.f, 0.f, 0.f};
    }

    // store FC result for step tf of `chain`
    auto store_fc = [&](int tf, int chain, const float4_t& facc) {
        int ntg = chain * 2 + nl;
        #pragma unroll
        for (int r = 0; r < 4; ++r)
            out[((size_t)(tf * OUT_F + 16 * m2 + 4 * g4 + r) << 14)
                + p0 + 16 * ntg + i16] = facc[r];
    };

    // standalone FC (epilogue): h in hB[hb]
    auto do_fc = [&](int tf, int hb, int chain) {
        int ntg = chain * 2 + nl;
        float4_t facc = fcb;
        #pragma unroll
        for (int kt = 0; kt < 4; ++kt) {
            short8_t b = *(const short8_t*)&hB[hb][kt * 4 + ntg][lane * 8];
            facc = __builtin_amdgcn_mfma_f32_16x16x32_bf16(
                fcfrag[kt], b, facc, 0, 0, 0);
        }
        store_fc(tf, chain, facc);
    };

    // gates = bias + W @ [x(xb); h(hb)] for `chain`; FC(t-1) merged on the
    // shared h fragments (kt 2..5) when nt == nl.
    auto gemm = [&](float4_t (&acc)[4][2], int xb, int hb, int chain,
                    float4_t& facc, bool fc_on) {
        #pragma unroll
        for (int gi = 0; gi < 4; ++gi)
            #pragma unroll
            for (int nt = 0; nt < 2; ++nt) acc[gi][nt] = bias_r[gi];
        #pragma unroll
        for (int nt = 0; nt < 2; ++nt) {
            int ntg = chain * 2 + nt;
            short8_t bf[6];
            #pragma unroll
            for (int kt = 0; kt < 6; ++kt) {
                const short* src = (kt < 2) ? &xB[xb][kt * 4 + ntg][0]
                                            : &hB[hb][(kt - 2) * 4 + ntg][0];
                bf[kt] = *(const short8_t*)&src[lane * 8];
            }
            #pragma unroll
            for (int kt = 0; kt < 6; ++kt)
                #pragma unroll
                for (int gi = 0; gi < 4; ++gi)
                    acc[gi][nt] = __builtin_amdgcn_mfma_f32_16x16x32_bf16(
                        wfrag[gi][kt], bf[kt], acc[gi][nt], 0, 0, 0);
            if (fc_on && nt == nl) {
                #pragma unroll
                for (int kt = 2; kt < 6; ++kt)
                    facc = __builtin_amdgcn_mfma_f32_16x16x32_bf16(
                        fcfrag[kt - 2], bf[kt], facc, 0, 0, 0);
            }
        }
    };

    // cell update (i,f,g,o) for `chain`; writes h into hB[hb]
    auto cell = [&](float4_t (&acc)[4][2], float4_t (&c)[2], int hb, int chain) {
        #pragma unroll
        for (int nt = 0; nt < 2; ++nt) {
            float4_t cv = c[nt];
            float hv[4];
            #pragma unroll
            for (int r = 0; r < 4; ++r) {
                float ig = sig2(acc[0][nt][r]);
                float fg = sig2(acc[1][nt][r]);
                float cand = th2(acc[2][nt][r]);
                float og = sig2(acc[3][nt][r]);
                float cn = fmaf(fg, cv[r], ig * cand);
                cv[r] = cn;
                hv[r] = og * th2(cn * (2.0f * L2E));
            }
            c[nt] = cv;
            uint32_t h0 = cvt_pk(hv[0], hv[1]);
            uint32_t h1 = cvt_pk(hv[2], hv[3]);
            uint32_t* dst = (uint32_t*)&hB[hb][htile_base + chain * 2 + nt][hoff];
            dst[0] = h0; dst[1] = h1;
        }
    };

    __syncthreads();   // cold: xB[0] ready, hB zeroed

    #pragma unroll 1
    for (int t = 0; t < T_STEPS; ++t) {
        const int cur = t & 1;
        const int nxt = cur ^ 1;   // holds h(t-1) of both chains

        // ======== P1: GEMM_A(t)+FC_A(t-1) + cell_B(t-1) ========
        float g[8];
        if (t < T_STEPS - 1) {
            #pragma unroll
            for (int e = 0; e < 8; ++e)
                g[e] = feats[((size_t)((t + 1) * C_IN + 8 * wv + e) << 16) + gbase];
        }
        float4_t faccA = fcb;
        gemm(accA, cur, nxt, 0, faccA, t > 0);
        if (t > 0) store_fc(t - 1, 0, faccA);
        if (t > 0) cell(accB, cB, nxt, 1);   // writes hB[nxt] tiles {2,3}

        barrier_lgkm();   // B1: LDS-only wait; gather loads/FC stores fly on

        // ======== P2: GEMM_B(t)+FC_B(t-1) + cell_A(t) ========
        float4_t faccB = fcb;
        gemm(accB, cur, nxt, 1, faccB, t > 0);
        if (t > 0) store_fc(t - 1, 1, faccB);
        cell(accA, cA, cur, 0);              // writes hB[cur] tiles {0,1}

        if (t < T_STEPS - 1) {
            uint4_t pk = { cvt_pk(g[0], g[1]), cvt_pk(g[2], g[3]),
                           cvt_pk(g[4], g[5]), cvt_pk(g[6], g[7]) };
            *(uint4_t*)&xB[nxt][xtile][xoff] = pk;
        }

        barrier_lgkm();   // B2
    }

    // epilogue: cell_B(31) -> hB[1]; FC of both chains for t=31 (h in hB[1])
    cell(accB, cB, 1, 1);
    __syncthreads();   // cold
    do_fc(T_STEPS - 1, 1, 0);
    do_fc(T_STEPS - 1, 1, 1);
}

extern "C" void kernel_launch(void* const* d_in, const int* in_sizes, int n_in,
                              void* d_out, int out_size, void* d_ws, size_t ws_size,
                              hipStream_t stream) {
    const float* feats = (const float*)d_in[0];
    const float* W_ih  = (const float*)d_in[1];
    const float* W_hh  = (const float*)d_in[2];
    const float* b_ih  = (const float*)d_in[3];
    const float* b_hh  = (const float*)d_in[4];
    const float* fc_w  = (const float*)d_in[5];
    const float* fc_b  = (const float*)d_in[6];
    float* out = (float*)d_out;

    lstmconv_mfma<<<NBLK, NTHR, 0, stream>>>(feats, W_ih, W_hh, b_ih, b_hh,
                                             fc_w, fc_b, out);
}